// Round 1
// baseline (412.294 us; speedup 1.0000x reference)
//
#include <hip/hip_runtime.h>
#include <math.h>

// Problem dims (fixed by the reference)
#define B_DIM 4096
#define F_DIM 1024
#define C_DIM 2047
#define DEPTH 11

// ---------------------------------------------------------------------------
// Kernel 1: e = x @ W^T + bias   (B,F) x (C,F)^T -> (B,C), f32
// 64x64 tile per block, BK=16, 256 threads, 4x4 register blocking.
// ---------------------------------------------------------------------------
#define BM 64
#define BN 64
#define BK 16

__global__ __launch_bounds__(256) void gemm_f32_kernel(
    const float* __restrict__ x,     // (B,F)
    const float* __restrict__ w,     // (C,F)
    const float* __restrict__ bias,  // (C)
    float* __restrict__ e)           // (B,C)
{
    __shared__ float As[BK][BM];
    __shared__ float Bs[BK][BN];

    const int bn = blockIdx.x;          // along C (32 blocks, last partial)
    const int bm = blockIdx.y;          // along B (64 blocks)
    const int tid = threadIdx.x;

    const int tx = tid & 15;            // 0..15 -> n
    const int ty = tid >> 4;            // 0..15 -> m
    const int m0 = ty * 4;
    const int n0 = tx * 4;

    // Cooperative load mapping: each thread loads one float4 of A and of B
    const int lrow = tid >> 2;          // 0..63
    const int lc4  = (tid & 3) * 4;     // 0,4,8,12

    const int gm = bm * BM + lrow;      // x row, always < 4096
    const int gn = bn * BN + lrow;      // w row, may be >= C_DIM
    const bool wvalid = (gn < C_DIM);

    const float* xp = x + (size_t)gm * F_DIM + lc4;
    const float* wp = wvalid ? (w + (size_t)gn * F_DIM + lc4) : w;

    float acc[4][4] = {};

    for (int k0 = 0; k0 < F_DIM; k0 += BK) {
        float4 av = *(const float4*)(xp + k0);
        float4 bv = make_float4(0.f, 0.f, 0.f, 0.f);
        if (wvalid) bv = *(const float4*)(wp + k0);

        As[lc4 + 0][lrow] = av.x;
        As[lc4 + 1][lrow] = av.y;
        As[lc4 + 2][lrow] = av.z;
        As[lc4 + 3][lrow] = av.w;
        Bs[lc4 + 0][lrow] = bv.x;
        Bs[lc4 + 1][lrow] = bv.y;
        Bs[lc4 + 2][lrow] = bv.z;
        Bs[lc4 + 3][lrow] = bv.w;
        __syncthreads();

#pragma unroll
        for (int k = 0; k < BK; ++k) {
            float4 a = *(const float4*)&As[k][m0];
            float4 b = *(const float4*)&Bs[k][n0];
            acc[0][0] += a.x * b.x; acc[0][1] += a.x * b.y;
            acc[0][2] += a.x * b.z; acc[0][3] += a.x * b.w;
            acc[1][0] += a.y * b.x; acc[1][1] += a.y * b.y;
            acc[1][2] += a.y * b.z; acc[1][3] += a.y * b.w;
            acc[2][0] += a.z * b.x; acc[2][1] += a.z * b.y;
            acc[2][2] += a.z * b.z; acc[2][3] += a.z * b.w;
            acc[3][0] += a.w * b.x; acc[3][1] += a.w * b.y;
            acc[3][2] += a.w * b.z; acc[3][3] += a.w * b.w;
        }
        __syncthreads();
    }

    const int gmo = bm * BM + m0;
    const int gno = bn * BN + n0;
#pragma unroll
    for (int i = 0; i < 4; ++i) {
#pragma unroll
        for (int j = 0; j < 4; ++j) {
            int n = gno + j;
            if (n < C_DIM) {
                e[(size_t)(gmo + i) * C_DIM + n] = acc[i][j] + bias[n];
            }
        }
    }
}

// ---------------------------------------------------------------------------
// Kernel 2: tree-CRF sum-product per batch row (in place on d_out).
// One block (256 threads) per batch row. All state in LDS (~41 KB).
// ---------------------------------------------------------------------------
__device__ __forceinline__ float lse2(float a, float b) {
    float m = fmaxf(a, b);
    float d = fminf(a, b) - m;
    return m + log1pf(__expf(d));
}

__global__ __launch_bounds__(256) void crf_kernel(
    const float* __restrict__ pairs,  // (C,C,2,2)
    float* __restrict__ eo)           // (B,C): e in, probability out
{
    __shared__ float se[C_DIM];          // emission scalar e (em = {-e, +e})
    __shared__ float alpha[C_DIM][2];
    __shared__ float beta[C_DIM][2];

    const int row = blockIdx.x;
    const int tid = threadIdx.x;
    float* erow = eo + (size_t)row * C_DIM;

    // Load e row + zero-init alpha/beta
    for (int c = tid; c < C_DIM; c += 256) {
        se[c] = erow[c];
        alpha[c][0] = 0.f; alpha[c][1] = 0.f;
        beta[c][0] = 0.f;  beta[c][1] = 0.f;
    }
    __syncthreads();

    // Upward: leaves -> root. One thread per PARENT (handles both children,
    // no scatter race). Parent level l-1 for child level l.
    for (int l = DEPTH - 1; l >= 1; --l) {
        const int pbase = (1 << (l - 1)) - 1;
        const int pcount = 1 << (l - 1);
        for (int p = pbase + tid; p < pbase + pcount; p += 256) {
            float a0 = 0.f, a1 = 0.f;
#pragma unroll
            for (int s = 1; s <= 2; ++s) {
                const int c = 2 * p + s;
                const float l0 = -se[c] + alpha[c][0];
                const float l1 =  se[c] + alpha[c][1];
                const float4 pe = *(const float4*)(pairs + ((size_t)p * C_DIM + c) * 4);
                // msg[yp] = lse over child label
                a0 += lse2(pe.x + l0, pe.y + l1);
                a1 += lse2(pe.z + l0, pe.w + l1);
            }
            alpha[p][0] = a0;
            alpha[p][1] = a1;
        }
        __syncthreads();
    }

    // Downward: root -> leaves. One thread per CHILD node.
    for (int l = 1; l < DEPTH; ++l) {
        const int cbase = (1 << l) - 1;
        const int ccount = 1 << l;
        for (int c = cbase + tid; c < cbase + ccount; c += 256) {
            const int p = (c - 1) >> 1;
            const float lp0 = -se[p] + beta[p][0];
            const float lp1 =  se[p] + beta[p][1];
            const float4 pe = *(const float4*)(pairs + ((size_t)p * C_DIM + c) * 4);
            // msg[yc] = lse over parent label
            beta[c][0] = lse2(lp0 + pe.x, lp1 + pe.z);
            beta[c][1] = lse2(lp0 + pe.y, lp1 + pe.w);
        }
        __syncthreads();
    }

    // scores = em + alpha + beta; out = softmax over 2 labels, take label 1
    // = sigmoid((em1-em0) + (a1-a0) + (b1-b0)) = sigmoid(2e + da + db)
    for (int c = tid; c < C_DIM; c += 256) {
        float d = 2.f * se[c] + (alpha[c][1] - alpha[c][0])
                              + (beta[c][1] - beta[c][0]);
        erow[c] = 1.f / (1.f + __expf(-d));
    }
}

// ---------------------------------------------------------------------------
extern "C" void kernel_launch(void* const* d_in, const int* in_sizes, int n_in,
                              void* d_out, int out_size, void* d_ws, size_t ws_size,
                              hipStream_t stream) {
    const float* x     = (const float*)d_in[0];  // (B,F)
    const float* w     = (const float*)d_in[1];  // (C,F)
    const float* bias  = (const float*)d_in[2];  // (C)
    const float* pairs = (const float*)d_in[3];  // (C,C,2,2)
    float* out = (float*)d_out;                  // (B,C)

    dim3 ggrid((C_DIM + BN - 1) / BN, B_DIM / BM);
    gemm_f32_kernel<<<ggrid, 256, 0, stream>>>(x, w, bias, out);

    crf_kernel<<<B_DIM, 256, 0, stream>>>(pairs, out);
}

// Round 2
// 148.484 us; speedup vs baseline: 2.7767x; 2.7767x over previous
//
#include <hip/hip_runtime.h>
#include <hip/hip_bf16.h>
#include <math.h>

// Problem dims (fixed by the reference)
#define B_DIM 4096
#define F_DIM 1024
#define C_DIM 2047
#define C_PAD 2048
#define DEPTH 11

typedef __attribute__((ext_vector_type(8))) short bf16x8;
typedef __attribute__((ext_vector_type(4))) float f32x4;

#define AS1(p) ((const __attribute__((address_space(1))) void*)(p))
#define AS3(p) ((__attribute__((address_space(3))) void*)(p))

// ---------------------------------------------------------------------------
// bf16 split helpers (RNE)
// ---------------------------------------------------------------------------
__device__ __forceinline__ unsigned short f2bf(float f) {
    unsigned int u = __float_as_uint(f);
    unsigned int r = (u + 0x7fffu + ((u >> 16) & 1u)) >> 16;
    return (unsigned short)r;
}
__device__ __forceinline__ float bf2f(unsigned short h) {
    return __uint_as_float(((unsigned int)h) << 16);
}

// ---------------------------------------------------------------------------
// Convert x (B,F) f32 -> xhi, xlo bf16
// ---------------------------------------------------------------------------
__global__ __launch_bounds__(256) void cvt_x_kernel(
    const float* __restrict__ x,
    unsigned short* __restrict__ hi, unsigned short* __restrict__ lo)
{
    const int i = (blockIdx.x * 256 + threadIdx.x) * 4;  // < B*F, divisible
    float4 v = *(const float4*)(x + i);
    ushort4 h, l;
    h.x = f2bf(v.x); l.x = f2bf(v.x - bf2f(h.x));
    h.y = f2bf(v.y); l.y = f2bf(v.y - bf2f(h.y));
    h.z = f2bf(v.z); l.z = f2bf(v.z - bf2f(h.z));
    h.w = f2bf(v.w); l.w = f2bf(v.w - bf2f(h.w));
    *(ushort4*)(hi + i) = h;
    *(ushort4*)(lo + i) = l;
}

// Convert w (C,F) f32 -> whi, wlo bf16 padded to C_PAD rows (row 2047 = 0)
__global__ __launch_bounds__(256) void cvt_w_kernel(
    const float* __restrict__ w,
    unsigned short* __restrict__ hi, unsigned short* __restrict__ lo)
{
    const int i = (blockIdx.x * 256 + threadIdx.x) * 4;  // < C_PAD*F
    const int row = i >> 10;                             // F = 1024
    ushort4 h = {0, 0, 0, 0}, l = {0, 0, 0, 0};
    if (row < C_DIM) {
        float4 v = *(const float4*)(w + i);
        h.x = f2bf(v.x); l.x = f2bf(v.x - bf2f(h.x));
        h.y = f2bf(v.y); l.y = f2bf(v.y - bf2f(h.y));
        h.z = f2bf(v.z); l.z = f2bf(v.z - bf2f(h.z));
        h.w = f2bf(v.w); l.w = f2bf(v.w - bf2f(h.w));
    }
    *(ushort4*)(hi + i) = h;
    *(ushort4*)(lo + i) = l;
}

// ---------------------------------------------------------------------------
// MFMA GEMM: e = x @ W^T + bias over 3 split-bf16 segments (effective K=3072)
// 128x128 tile, BK=32, 256 threads (4 waves, 2x2), 16x16x32 bf16 MFMA.
// global_load_lds (16B) staging with chunk-XOR swizzle via pre-swizzled src.
// ---------------------------------------------------------------------------
__global__ __launch_bounds__(256) void gemm_mfma_kernel(
    const unsigned short* __restrict__ xhi, const unsigned short* __restrict__ xlo,
    const unsigned short* __restrict__ whi, const unsigned short* __restrict__ wlo,
    const float* __restrict__ bias, float* __restrict__ e)
{
    __shared__ unsigned short smemA[128 * 32];  // [row][k] 64B rows
    __shared__ unsigned short smemB[128 * 32];

    const int tid  = threadIdx.x;
    const int lane = tid & 63;
    const int wave = tid >> 6;
    const int wr = wave >> 1, wc = wave & 1;
    const int bn = blockIdx.x, bm = blockIdx.y;

    f32x4 acc[4][4] = {};

    // staging slots: slot s = i*256 + tid; row = s>>2, chunk16B = s&3
    // LDS slot (row, c) holds global chunk (row, c ^ (row&3))  [read-side XOR]
    const int s0 = tid, s1 = tid + 256;
    const int r0 = s0 >> 2, c0 = s0 & 3;
    const int r1 = s1 >> 2, c1 = s1 & 3;
    const int sc0 = ((c0 ^ (r0 & 3)) << 3);  // element offset within k-tile
    const int sc1 = ((c1 ^ (r1 & 3)) << 3);

    const size_t arow0 = (size_t)(bm * 128 + r0) * F_DIM;
    const size_t arow1 = (size_t)(bm * 128 + r1) * F_DIM;
    const size_t brow0 = (size_t)(bn * 128 + r0) * F_DIM;
    const size_t brow1 = (size_t)(bn * 128 + r1) * F_DIM;

    // wave-uniform LDS bases (ushort offsets): i*2048 + wave*512
    unsigned short* ldsA0 = smemA + wave * 512;
    unsigned short* ldsA1 = smemA + 2048 + wave * 512;
    unsigned short* ldsB0 = smemB + wave * 512;
    unsigned short* ldsB1 = smemB + 2048 + wave * 512;

    // fragment read offsets (ushort), swizzled chunk
    const int fra = wr * 64 + (lane & 15);   // A row base (+m*16)
    const int frb = wc * 64 + (lane & 15);   // B row base (+n*16)
    const int kc  = lane >> 4;               // 16B chunk 0..3

    for (int seg = 0; seg < 3; ++seg) {
        const unsigned short* Ap = (seg == 2) ? xlo : xhi;
        const unsigned short* Bp = (seg == 1) ? wlo : whi;
        for (int k0 = 0; k0 < F_DIM; k0 += 32) {
            __builtin_amdgcn_global_load_lds(AS1(Ap + arow0 + k0 + sc0), AS3(ldsA0), 16, 0, 0);
            __builtin_amdgcn_global_load_lds(AS1(Ap + arow1 + k0 + sc1), AS3(ldsA1), 16, 0, 0);
            __builtin_amdgcn_global_load_lds(AS1(Bp + brow0 + k0 + sc0), AS3(ldsB0), 16, 0, 0);
            __builtin_amdgcn_global_load_lds(AS1(Bp + brow1 + k0 + sc1), AS3(ldsB1), 16, 0, 0);
            __syncthreads();

            bf16x8 af[4], bf[4];
#pragma unroll
            for (int m = 0; m < 4; ++m) {
                const int row = fra + m * 16;
                af[m] = *(const bf16x8*)(smemA + row * 32 + ((kc ^ (row & 3)) << 3));
            }
#pragma unroll
            for (int n = 0; n < 4; ++n) {
                const int row = frb + n * 16;
                bf[n] = *(const bf16x8*)(smemB + row * 32 + ((kc ^ (row & 3)) << 3));
            }
#pragma unroll
            for (int m = 0; m < 4; ++m)
#pragma unroll
                for (int n = 0; n < 4; ++n)
                    acc[m][n] = __builtin_amdgcn_mfma_f32_16x16x32_bf16(
                        af[m], bf[n], acc[m][n], 0, 0, 0);
            __syncthreads();
        }
    }

    // Epilogue: C/D layout col = lane&15, row = (lane>>4)*4 + r
    const int colbase = bn * 128 + wc * 64 + (lane & 15);
    const int rowbase = bm * 128 + wr * 64 + ((lane >> 4) << 2);
#pragma unroll
    for (int m = 0; m < 4; ++m) {
#pragma unroll
        for (int n = 0; n < 4; ++n) {
            const int gc = colbase + n * 16;
            if (gc < C_DIM) {
                const float bv = bias[gc];
#pragma unroll
                for (int r = 0; r < 4; ++r) {
                    const int gr = rowbase + m * 16 + r;
                    e[(size_t)gr * C_DIM + gc] = acc[m][n][r] + bv;
                }
            }
        }
    }
}

// ---------------------------------------------------------------------------
// Fallback f32 GEMM (used only if ws_size is too small for bf16 split bufs)
// ---------------------------------------------------------------------------
#define BMF 64
#define BNF 64
#define BKF 16

__global__ __launch_bounds__(256) void gemm_f32_kernel(
    const float* __restrict__ x, const float* __restrict__ w,
    const float* __restrict__ bias, float* __restrict__ e)
{
    __shared__ float As[BKF][BMF];
    __shared__ float Bs[BKF][BNF];
    const int bn = blockIdx.x, bm = blockIdx.y;
    const int tid = threadIdx.x;
    const int tx = tid & 15, ty = tid >> 4;
    const int m0 = ty * 4, n0 = tx * 4;
    const int lrow = tid >> 2, lc4 = (tid & 3) * 4;
    const int gm = bm * BMF + lrow;
    const int gn = bn * BNF + lrow;
    const bool wvalid = (gn < C_DIM);
    const float* xp = x + (size_t)gm * F_DIM + lc4;
    const float* wp = wvalid ? (w + (size_t)gn * F_DIM + lc4) : w;
    float acc[4][4] = {};
    for (int k0 = 0; k0 < F_DIM; k0 += BKF) {
        float4 av = *(const float4*)(xp + k0);
        float4 bv = make_float4(0.f, 0.f, 0.f, 0.f);
        if (wvalid) bv = *(const float4*)(wp + k0);
        As[lc4 + 0][lrow] = av.x; As[lc4 + 1][lrow] = av.y;
        As[lc4 + 2][lrow] = av.z; As[lc4 + 3][lrow] = av.w;
        Bs[lc4 + 0][lrow] = bv.x; Bs[lc4 + 1][lrow] = bv.y;
        Bs[lc4 + 2][lrow] = bv.z; Bs[lc4 + 3][lrow] = bv.w;
        __syncthreads();
#pragma unroll
        for (int k = 0; k < BKF; ++k) {
            float4 a = *(const float4*)&As[k][m0];
            float4 b = *(const float4*)&Bs[k][n0];
            acc[0][0] += a.x * b.x; acc[0][1] += a.x * b.y; acc[0][2] += a.x * b.z; acc[0][3] += a.x * b.w;
            acc[1][0] += a.y * b.x; acc[1][1] += a.y * b.y; acc[1][2] += a.y * b.z; acc[1][3] += a.y * b.w;
            acc[2][0] += a.z * b.x; acc[2][1] += a.z * b.y; acc[2][2] += a.z * b.z; acc[2][3] += a.z * b.w;
            acc[3][0] += a.w * b.x; acc[3][1] += a.w * b.y; acc[3][2] += a.w * b.z; acc[3][3] += a.w * b.w;
        }
        __syncthreads();
    }
    const int gmo = bm * BMF + m0, gno = bn * BNF + n0;
#pragma unroll
    for (int i = 0; i < 4; ++i)
#pragma unroll
        for (int j = 0; j < 4; ++j) {
            int n = gno + j;
            if (n < C_DIM) e[(size_t)(gmo + i) * C_DIM + n] = acc[i][j] + bias[n];
        }
}

// ---------------------------------------------------------------------------
// Tree-CRF sum-product per batch row (in place on d_out)
// ---------------------------------------------------------------------------
__device__ __forceinline__ float lse2(float a, float b) {
    float m = fmaxf(a, b);
    float d = fminf(a, b) - m;
    return m + __logf(1.f + __expf(d));
}

__global__ __launch_bounds__(256) void crf_kernel(
    const float* __restrict__ pairs,  // (C,C,2,2)
    float* __restrict__ eo)           // (B,C): e in, probability out
{
    __shared__ float se[C_DIM];
    __shared__ float alpha[C_DIM][2];
    __shared__ float beta[C_DIM][2];

    const int row = blockIdx.x;
    const int tid = threadIdx.x;
    float* erow = eo + (size_t)row * C_DIM;

    for (int c = tid; c < C_DIM; c += 256) {
        se[c] = erow[c];
        alpha[c][0] = 0.f; alpha[c][1] = 0.f;
        beta[c][0] = 0.f;  beta[c][1] = 0.f;
    }
    __syncthreads();

    // Upward: one thread per parent (both children, no scatter race)
    for (int l = DEPTH - 1; l >= 1; --l) {
        const int pbase = (1 << (l - 1)) - 1;
        const int pcount = 1 << (l - 1);
        for (int p = pbase + tid; p < pbase + pcount; p += 256) {
            float a0 = 0.f, a1 = 0.f;
#pragma unroll
            for (int s = 1; s <= 2; ++s) {
                const int c = 2 * p + s;
                const float l0 = -se[c] + alpha[c][0];
                const float l1 =  se[c] + alpha[c][1];
                const float4 pe = *(const float4*)(pairs + ((size_t)p * C_DIM + c) * 4);
                a0 += lse2(pe.x + l0, pe.y + l1);
                a1 += lse2(pe.z + l0, pe.w + l1);
            }
            alpha[p][0] = a0;
            alpha[p][1] = a1;
        }
        __syncthreads();
    }

    // Downward: one thread per child
    for (int l = 1; l < DEPTH; ++l) {
        const int cbase = (1 << l) - 1;
        const int ccount = 1 << l;
        for (int c = cbase + tid; c < cbase + ccount; c += 256) {
            const int p = (c - 1) >> 1;
            const float lp0 = -se[p] + beta[p][0];
            const float lp1 =  se[p] + beta[p][1];
            const float4 pe = *(const float4*)(pairs + ((size_t)p * C_DIM + c) * 4);
            beta[c][0] = lse2(lp0 + pe.x, lp1 + pe.z);
            beta[c][1] = lse2(lp0 + pe.y, lp1 + pe.w);
        }
        __syncthreads();
    }

    for (int c = tid; c < C_DIM; c += 256) {
        float d = 2.f * se[c] + (alpha[c][1] - alpha[c][0])
                              + (beta[c][1] - beta[c][0]);
        erow[c] = 1.f / (1.f + __expf(-d));
    }
}

// ---------------------------------------------------------------------------
extern "C" void kernel_launch(void* const* d_in, const int* in_sizes, int n_in,
                              void* d_out, int out_size, void* d_ws, size_t ws_size,
                              hipStream_t stream) {
    const float* x     = (const float*)d_in[0];  // (B,F)
    const float* w     = (const float*)d_in[1];  // (C,F)
    const float* bias  = (const float*)d_in[2];  // (C)
    const float* pairs = (const float*)d_in[3];  // (C,C,2,2)
    float* out = (float*)d_out;                  // (B,C)

    const size_t need = (size_t)2 * B_DIM * F_DIM * 2   // xhi+xlo
                      + (size_t)2 * C_PAD * F_DIM * 2;  // whi+wlo
    if (ws_size >= need) {
        unsigned short* xhi = (unsigned short*)d_ws;
        unsigned short* xlo = xhi + (size_t)B_DIM * F_DIM;
        unsigned short* whi = xlo + (size_t)B_DIM * F_DIM;
        unsigned short* wlo = whi + (size_t)C_PAD * F_DIM;

        cvt_x_kernel<<<(B_DIM * F_DIM) / (256 * 4), 256, 0, stream>>>(x, xhi, xlo);
        cvt_w_kernel<<<(C_PAD * F_DIM) / (256 * 4), 256, 0, stream>>>(w, whi, wlo);

        dim3 ggrid(C_PAD / 128, B_DIM / 128);
        gemm_mfma_kernel<<<ggrid, 256, 0, stream>>>(xhi, xlo, whi, wlo, bias, out);
    } else {
        dim3 ggrid((C_DIM + BNF - 1) / BNF, B_DIM / BMF);
        gemm_f32_kernel<<<ggrid, 256, 0, stream>>>(x, w, bias, out);
    }

    crf_kernel<<<B_DIM, 256, 0, stream>>>(pairs, out);
}